// Round 2
// baseline (977.762 us; speedup 1.0000x reference)
//
#include <hip/hip_runtime.h>

#define N_NODES 32000
#define NPG     1000
#define BSZ     32
#define NEDGE   512000
#define H       128
#define NL      3
#define NR      8
#define KCH     64   // GEMM k-chunk

// ---------------- CSR build (by dst), payload = src*8 | etype ----------------
__global__ void k_count(const int* __restrict__ dst, int* __restrict__ cnt) {
  int e = blockIdx.x * blockDim.x + threadIdx.x;
  if (e < NEDGE) atomicAdd(&cnt[dst[e]], 1);
}

__global__ void k_scan(int* __restrict__ cursor /*in counts, out start*/, int* __restrict__ row_ptr) {
  __shared__ int ssum[256];
  __shared__ int soff[256];
  const int tid = threadIdx.x;
  const int CH = N_NODES / 256;  // 125
  const int base = tid * CH;
  int s = 0;
  for (int i = 0; i < CH; ++i) s += cursor[base + i];
  ssum[tid] = s;
  __syncthreads();
  if (tid == 0) {
    int r = 0;
    for (int i = 0; i < 256; ++i) { soff[i] = r; r += ssum[i]; }
    row_ptr[N_NODES] = r;
  }
  __syncthreads();
  int off = soff[tid];
  for (int i = 0; i < CH; ++i) {
    int c = cursor[base + i];
    row_ptr[base + i] = off;
    cursor[base + i] = off;   // cursor for fill
    off += c;
  }
}

__global__ void k_fill(const int* __restrict__ src, const int* __restrict__ dst,
                       const int* __restrict__ etype, int* __restrict__ cursor,
                       int* __restrict__ edge_dat) {
  int e = blockIdx.x * blockDim.x + threadIdx.x;
  if (e < NEDGE) {
    int p = atomicAdd(&cursor[dst[e]], 1);
    edge_dat[p] = (src[e] << 3) | etype[e];
  }
}

__global__ void k_gcount(const int* __restrict__ graph_id, int* __restrict__ gcount) {
  int n = blockIdx.x * blockDim.x + threadIdx.x;
  if (n < N_NODES) atomicAdd(&gcount[graph_id[n]], 1);
}

// ---------------- per-node gather-aggregate: agg[n, r*H + i] ----------------
__global__ __launch_bounds__(256) void k_agg(
    const float* __restrict__ h, const int* __restrict__ row_ptr,
    const int* __restrict__ edge_dat, float* __restrict__ agg)
{
  const int node = blockIdx.x * 4 + (threadIdx.x >> 6);
  const int lane = threadIdx.x & 63;
  const int c0 = lane * 2;
  float2 a0 = {0.f,0.f}, a1 = {0.f,0.f}, a2 = {0.f,0.f}, a3 = {0.f,0.f};
  float2 a4 = {0.f,0.f}, a5 = {0.f,0.f}, a6 = {0.f,0.f}, a7 = {0.f,0.f};
  const int beg = row_ptr[node];
  const int end = row_ptr[node + 1];
  for (int e = beg; e < end; ++e) {
    const int v = __builtin_amdgcn_readfirstlane(edge_dat[e]);   // wave-uniform
    const float2 p = *(const float2*)(h + (size_t)(v >> 3) * H + c0);
    switch (v & 7) {   // uniform branch
      case 0: a0.x += p.x; a0.y += p.y; break;
      case 1: a1.x += p.x; a1.y += p.y; break;
      case 2: a2.x += p.x; a2.y += p.y; break;
      case 3: a3.x += p.x; a3.y += p.y; break;
      case 4: a4.x += p.x; a4.y += p.y; break;
      case 5: a5.x += p.x; a5.y += p.y; break;
      case 6: a6.x += p.x; a6.y += p.y; break;
      case 7: a7.x += p.x; a7.y += p.y; break;
    }
  }
  float* o = agg + (size_t)node * (NR * H) + c0;
  *(float2*)(o + 0*H) = a0; *(float2*)(o + 1*H) = a1;
  *(float2*)(o + 2*H) = a2; *(float2*)(o + 3*H) = a3;
  *(float2*)(o + 4*H) = a4; *(float2*)(o + 5*H) = a5;
  *(float2*)(o + 6*H) = a6; *(float2*)(o + 7*H) = a7;
}

// ---------------- fused GEMM: relu([agg | h] @ [Wrel ; Wself]) -> repr_l ----------------
// M=32000, K=1152, N=128. Tile 128x64, 256 threads, per-thread 4x8.
__global__ __launch_bounds__(256) void k_gemm(
    const float* __restrict__ Aagg,              // [N, 1024] fp32
    const float* __restrict__ Ah,                // [N, 128]  fp32
    const float* __restrict__ Bw,                // [1024, 128] fp32 (W_rel[l] flattened r,i -> o)
    const float* __restrict__ Bs,                // [128, 128]  fp32 (W_self[l])
    float* __restrict__ Cout)                    // [N, 128] fp32 (repr_l)
{
  __shared__ float lds_a[128 * 68];   // [m][k] row stride 68 (16B-aligned, low conflict)
  __shared__ float lds_b[64 * 64];    // [k][n]
  const int tid = threadIdx.x;
  const int m0 = blockIdx.x * 128;
  const int n0 = blockIdx.y * 64;
  const int tx = tid & 7;    // 8 -> 8 cols each = 64
  const int ty = tid >> 3;   // 32 -> 4 rows each = 128
  float acc[4][8];
  #pragma unroll
  for (int i = 0; i < 4; ++i)
    #pragma unroll
    for (int j = 0; j < 8; ++j) acc[i][j] = 0.f;

  for (int kc = 0; kc < 1152; kc += KCH) {
    __syncthreads();
    // stage A: 128 rows x 64 cols (chunks never straddle the agg/h boundary)
    const float* Ap; size_t lda; int kb;
    if (kc < 1024) { Ap = Aagg; lda = 1024; kb = kc; }
    else           { Ap = Ah;   lda = H;    kb = kc - 1024; }
    #pragma unroll
    for (int s = 0; s < 8; ++s) {
      int f = s * 256 + tid;
      int m  = f >> 4;
      int k4 = (f & 15) << 2;
      float4 v = *(const float4*)(Ap + (size_t)(m0 + m) * lda + kb + k4);
      *(float4*)(lds_a + m * 68 + k4) = v;
    }
    // stage B: 64 rows x 64 cols
    const float* Bp = (kc < 1024) ? (Bw + (size_t)kc * H + n0)
                                  : (Bs + (size_t)(kc - 1024) * H + n0);
    #pragma unroll
    for (int s = 0; s < 4; ++s) {
      int f = s * 256 + tid;
      int kr = f >> 4;
      int n4 = (f & 15) << 2;
      float4 v = *(const float4*)(Bp + (size_t)kr * H + n4);
      *(float4*)(lds_b + kr * 64 + n4) = v;
    }
    __syncthreads();
    for (int k0 = 0; k0 < KCH; k0 += 4) {
      float areg[4][4];
      #pragma unroll
      for (int i = 0; i < 4; ++i) {
        float4 v = *(const float4*)(lds_a + (ty * 4 + i) * 68 + k0);
        areg[i][0] = v.x; areg[i][1] = v.y; areg[i][2] = v.z; areg[i][3] = v.w;
      }
      #pragma unroll
      for (int kk = 0; kk < 4; ++kk) {
        float4 b0 = *(const float4*)(lds_b + (k0 + kk) * 64 + tx * 8);
        float4 b1 = *(const float4*)(lds_b + (k0 + kk) * 64 + tx * 8 + 4);
        float breg[8] = {b0.x,b0.y,b0.z,b0.w,b1.x,b1.y,b1.z,b1.w};
        #pragma unroll
        for (int i = 0; i < 4; ++i)
          #pragma unroll
          for (int j = 0; j < 8; ++j)
            acc[i][j] = fmaf(areg[i][kk], breg[j], acc[i][j]);
      }
    }
  }
  #pragma unroll
  for (int i = 0; i < 4; ++i) {
    float4 o0, o1;
    o0.x = fmaxf(acc[i][0], 0.f); o0.y = fmaxf(acc[i][1], 0.f);
    o0.z = fmaxf(acc[i][2], 0.f); o0.w = fmaxf(acc[i][3], 0.f);
    o1.x = fmaxf(acc[i][4], 0.f); o1.y = fmaxf(acc[i][5], 0.f);
    o1.z = fmaxf(acc[i][6], 0.f); o1.w = fmaxf(acc[i][7], 0.f);
    float* d = Cout + (size_t)(m0 + ty * 4 + i) * H + n0 + tx * 8;
    *(float4*)d = o0;
    *(float4*)(d + 4) = o1;
  }
}

// ---------------- per-graph mean of repr ----------------
__global__ void k_gmean(const float* __restrict__ repr, const int* __restrict__ gcount,
                        float* __restrict__ gmean)
{
  const int g = blockIdx.x, l = blockIdx.y, o = threadIdx.x;
  const float* base = repr + ((size_t)l * N_NODES + (size_t)g * NPG) * H + o;
  float s0 = 0.f, s1 = 0.f, s2 = 0.f, s3 = 0.f;
  for (int i = 0; i < NPG; i += 4) {
    s0 += base[(size_t)(i + 0) * H];
    s1 += base[(size_t)(i + 1) * H];
    s2 += base[(size_t)(i + 2) * H];
    s3 += base[(size_t)(i + 3) * H];
  }
  gmean[(size_t)g * (NL * H) + l * H + o] = ((s0 + s1) + (s2 + s3)) / (float)gcount[g];
}

// ---------------- readout: proj / clusters / view attention / fc ----------------
__global__ __launch_bounds__(128) void k_final(
    const float* __restrict__ repr, const float* __restrict__ gmean,
    const float* __restrict__ rel_tb, const float* __restrict__ Zn,
    const float* __restrict__ projW, const float* __restrict__ projB,
    const float* __restrict__ fcW, const float* __restrict__ fcB,
    const float* __restrict__ repSeq,
    const int* __restrict__ head_ids, const int* __restrict__ tail_ids,
    const int* __restrict__ rel_lab, float* __restrict__ out)
{
  const int b = blockIdx.x;
  const int o = threadIdx.x;   // 128
  __shared__ float gm[384], hf[384], tf[384];
  __shared__ float go[128], ho[128], t_o[128], re[128], rs[128], sv[128];
  __shared__ float lg[128], pr[128], red[128], att[3];

  const int hid = head_ids[b], tlid = tail_ids[b], rl = rel_lab[b];
  #pragma unroll
  for (int l = 0; l < NL; ++l) {
    gm[l * H + o] = gmean[(size_t)b * (NL * H) + l * H + o];
    hf[l * H + o] = repr[((size_t)l * N_NODES + hid) * H + o];
    tf[l * H + o] = repr[((size_t)l * N_NODES + tlid) * H + o];
  }
  re[o] = rel_tb[rl * H + o];
  rs[o] = repSeq[b * H + o];
  __syncthreads();

  // g_out (leaky_relu 0.01), h_out, t_out = {gm,hf,tf} @ proj_W + proj_b
  float pb = projB[o];
  float sg = pb, sh = pb, st = pb;
  for (int i = 0; i < NL * H; ++i) {
    float wv = projW[i * H + o];
    sg = fmaf(gm[i], wv, sg);
    sh = fmaf(hf[i], wv, sh);
    st = fmaf(tf[i], wv, st);
  }
  go[o] = (sg > 0.f) ? sg : 0.01f * sg;
  ho[o] = sh;
  t_o[o] = st;
  __syncthreads();

  // cluster logits: threads 0..63 -> h, 64..127 -> t
  {
    const int k = o & 63;
    const float* v = (o < 64) ? ho : t_o;
    float s = 0.f;
    for (int i = 0; i < H; ++i) s = fmaf(v[i], Zn[k * H + i], s);
    lg[o] = s;
  }
  __syncthreads();
  if (o < 2) {   // softmax over 64 clusters (h and t)
    float* l0 = &lg[o * 64];
    float* p0 = &pr[o * 64];
    float mx = l0[0];
    for (int k = 1; k < 64; ++k) mx = fmaxf(mx, l0[k]);
    float sum = 0.f;
    for (int k = 0; k < 64; ++k) { float e = __expf(l0[k] - mx); p0[k] = e; sum += e; }
    float inv = 1.f / sum;
    for (int k = 0; k < 64; ++k) p0[k] *= inv;
  }
  __syncthreads();
  {
    float s1 = 0.f, s2 = 0.f;
    for (int k = 0; k < 64; ++k) {
      float z = Zn[k * H + o];
      s1 = fmaf(pr[k], z, s1);
      s2 = fmaf(pr[64 + k], z, s2);
    }
    s1 = 1.f / (1.f + __expf(-s1));
    s2 = 1.f / (1.f + __expf(-s2));
    sv[o] = s1 * s2;
  }
  __syncthreads();
  if (o == 0) {   // view attention (3 views)
    float d0 = 0.f, d1 = 0.f, d2 = 0.f;
    for (int i = 0; i < H; ++i) { d0 += re[i] * go[i]; d1 += re[i] * rs[i]; d2 += re[i] * sv[i]; }
    float mx = fmaxf(d0, fmaxf(d1, d2));
    float e0 = __expf(d0 - mx), e1 = __expf(d1 - mx), e2 = __expf(d2 - mx);
    float inv = 1.f / (e0 + e1 + e2);
    att[0] = e0 * inv; att[1] = e1 * inv; att[2] = e2 * inv;
  }
  __syncthreads();
  float va = att[0] * go[o] + att[1] * rs[o] + att[2] * sv[o];

  // g_rep = [hf(384) | tf(384) | re(128) | va(128)] . fc_W
  float p = 0.f;
  p = fmaf(hf[o],       fcW[o],       p);
  p = fmaf(hf[128 + o], fcW[128 + o], p);
  p = fmaf(hf[256 + o], fcW[256 + o], p);
  p = fmaf(tf[o],       fcW[384 + o], p);
  p = fmaf(tf[128 + o], fcW[512 + o], p);
  p = fmaf(tf[256 + o], fcW[640 + o], p);
  p = fmaf(re[o],       fcW[768 + o], p);
  p = fmaf(va,          fcW[896 + o], p);
  red[o] = p;
  __syncthreads();
  if (o == 0) {
    float s = 0.f;
    for (int i = 0; i < 128; ++i) s += red[i];
    out[b] = s + fcB[0];
  }
}

extern "C" void kernel_launch(void* const* d_in, const int* in_sizes, int n_in,
                              void* d_out, int out_size, void* d_ws, size_t ws_size,
                              hipStream_t stream) {
  const float* x        = (const float*)d_in[0];
  const float* W_rel    = (const float*)d_in[1];
  const float* W_self   = (const float*)d_in[2];
  const float* rel_tb   = (const float*)d_in[3];
  const float* Zn       = (const float*)d_in[4];
  const float* proj_W   = (const float*)d_in[5];
  const float* proj_b   = (const float*)d_in[6];
  const float* fc_W     = (const float*)d_in[7];
  const float* fc_b     = (const float*)d_in[8];
  const float* rep_seq  = (const float*)d_in[9];
  const int* src      = (const int*)d_in[10];
  const int* dst      = (const int*)d_in[11];
  const int* etype    = (const int*)d_in[12];
  const int* graph_id = (const int*)d_in[13];
  const int* head_ids = (const int*)d_in[14];
  const int* tail_ids = (const int*)d_in[15];
  const int* rel_lab  = (const int*)d_in[16];
  float* out = (float*)d_out;

  // workspace carve (~183 MB), all 16B aligned
  char* w = (char*)d_ws;
  float* agg   = (float*)w; w += (size_t)N_NODES * 1024 * 4;      // 131.07 MB
  float* repr  = (float*)w; w += (size_t)NL * N_NODES * H * 4;    //  49.15 MB
  float* gmean = (float*)w; w += (size_t)BSZ * NL * H * 4;
  int* row_ptr = (int*)w;   w += (size_t)32004 * 4;
  int* cursor  = (int*)w;   w += (size_t)N_NODES * 4;
  int* gcount  = (int*)w;   w += (size_t)32 * 4;
  int* edge_dat= (int*)w;   w += (size_t)NEDGE * 4;

  hipMemsetAsync(cursor, 0, (N_NODES + 32) * 4, stream);          // cursor + gcount
  k_count <<<NEDGE / 256, 256, 0, stream>>>(dst, cursor);
  k_scan  <<<1, 256, 0, stream>>>(cursor, row_ptr);
  k_fill  <<<NEDGE / 256, 256, 0, stream>>>(src, dst, etype, cursor, edge_dat);
  k_gcount<<<N_NODES / 256, 256, 0, stream>>>(graph_id, gcount);

  for (int l = 0; l < NL; ++l) {
    const float* hp = (l == 0) ? x : (repr + (size_t)(l - 1) * N_NODES * H);
    float* hout = repr + (size_t)l * N_NODES * H;
    k_agg <<<N_NODES / 4, 256, 0, stream>>>(hp, row_ptr, edge_dat, agg);
    k_gemm<<<dim3(N_NODES / 128, 2), 256, 0, stream>>>(
        agg, hp,
        W_rel + (size_t)l * NR * H * H,
        W_self + (size_t)l * H * H,
        hout);
  }
  k_gmean<<<dim3(BSZ, NL), H, 0, stream>>>(repr, gcount, gmean);
  k_final<<<BSZ, H, 0, stream>>>(repr, gmean, rel_tb, Zn, proj_W, proj_b, fc_W, fc_b,
                                 rep_seq, head_ids, tail_ids, rel_lab, out);
  (void)in_sizes; (void)n_in; (void)out_size; (void)ws_size;
}

// Round 3
// 825.535 us; speedup vs baseline: 1.1844x; 1.1844x over previous
//
#include <hip/hip_runtime.h>

#define N_NODES 32000
#define NPG     1000
#define BSZ     32
#define NEDGE   512000
#define H       128
#define NL      3
#define NR      8
#define KCH     64   // GEMM k-chunk

// ---------------- CSR build (by dst), payload = src*8 | etype ----------------
__global__ void k_count(const int* __restrict__ dst, int* __restrict__ cnt) {
  int e = blockIdx.x * blockDim.x + threadIdx.x;
  if (e < NEDGE) atomicAdd(&cnt[dst[e]], 1);
}

__global__ void k_scan(int* __restrict__ cursor /*in counts, out start*/, int* __restrict__ row_ptr) {
  __shared__ int ssum[256];
  __shared__ int soff[256];
  const int tid = threadIdx.x;
  const int CH = N_NODES / 256;  // 125
  const int base = tid * CH;
  int s = 0;
  for (int i = 0; i < CH; ++i) s += cursor[base + i];
  ssum[tid] = s;
  __syncthreads();
  if (tid == 0) {
    int r = 0;
    for (int i = 0; i < 256; ++i) { soff[i] = r; r += ssum[i]; }
    row_ptr[N_NODES] = r;
  }
  __syncthreads();
  int off = soff[tid];
  for (int i = 0; i < CH; ++i) {
    int c = cursor[base + i];
    row_ptr[base + i] = off;
    cursor[base + i] = off;   // cursor for fill
    off += c;
  }
}

__global__ void k_fill(const int* __restrict__ src, const int* __restrict__ dst,
                       const int* __restrict__ etype, int* __restrict__ cursor,
                       int* __restrict__ edge_dat) {
  int e = blockIdx.x * blockDim.x + threadIdx.x;
  if (e < NEDGE) {
    int p = atomicAdd(&cursor[dst[e]], 1);
    edge_dat[p] = (src[e] << 3) | etype[e];
  }
}

// run-length LDS histogram: graph_id is sorted (arange//NPG) so each thread's
// 125-element chunk spans <=2 runs -> ~2 LDS atomics/thread instead of 32000
// serialized global atomics on 2 cache lines (the 194us R2 pathology).
__global__ void k_gcount(const int* __restrict__ graph_id, int* __restrict__ gcount) {
  __shared__ int hist[BSZ];
  const int tid = threadIdx.x;  // 256
  if (tid < BSZ) hist[tid] = 0;
  __syncthreads();
  const int CH = N_NODES / 256;  // 125
  const int base = tid * CH;
  int cur = graph_id[base];
  int run = 1;
  for (int i = 1; i < CH; ++i) {
    int g = graph_id[base + i];
    if (g == cur) { ++run; }
    else { atomicAdd(&hist[cur], run); cur = g; run = 1; }
  }
  atomicAdd(&hist[cur], run);
  __syncthreads();
  if (tid < BSZ) gcount[tid] = hist[tid];
}

// ---------------- per-node gather-aggregate: agg[n, r*H + i] ----------------
__global__ __launch_bounds__(256) void k_agg(
    const float* __restrict__ h, const int* __restrict__ row_ptr,
    const int* __restrict__ edge_dat, float* __restrict__ agg)
{
  const int node = blockIdx.x * 4 + (threadIdx.x >> 6);
  const int lane = threadIdx.x & 63;
  const int c0 = lane * 2;
  float2 a0 = {0.f,0.f}, a1 = {0.f,0.f}, a2 = {0.f,0.f}, a3 = {0.f,0.f};
  float2 a4 = {0.f,0.f}, a5 = {0.f,0.f}, a6 = {0.f,0.f}, a7 = {0.f,0.f};
  const int beg = row_ptr[node];
  const int end = row_ptr[node + 1];
  for (int e = beg; e < end; ++e) {
    const int v = __builtin_amdgcn_readfirstlane(edge_dat[e]);   // wave-uniform
    const float2 p = *(const float2*)(h + (size_t)(v >> 3) * H + c0);
    switch (v & 7) {   // uniform branch
      case 0: a0.x += p.x; a0.y += p.y; break;
      case 1: a1.x += p.x; a1.y += p.y; break;
      case 2: a2.x += p.x; a2.y += p.y; break;
      case 3: a3.x += p.x; a3.y += p.y; break;
      case 4: a4.x += p.x; a4.y += p.y; break;
      case 5: a5.x += p.x; a5.y += p.y; break;
      case 6: a6.x += p.x; a6.y += p.y; break;
      case 7: a7.x += p.x; a7.y += p.y; break;
    }
  }
  float* o = agg + (size_t)node * (NR * H) + c0;
  *(float2*)(o + 0*H) = a0; *(float2*)(o + 1*H) = a1;
  *(float2*)(o + 2*H) = a2; *(float2*)(o + 3*H) = a3;
  *(float2*)(o + 4*H) = a4; *(float2*)(o + 5*H) = a5;
  *(float2*)(o + 6*H) = a6; *(float2*)(o + 7*H) = a7;
}

// ---------------- fused GEMM: relu([agg | h] @ [Wrel ; Wself]) -> repr_l ----------------
// M=32000, K=1152, N=128. Tile 128x64, 256 threads, per-thread 4x8.
__global__ __launch_bounds__(256) void k_gemm(
    const float* __restrict__ Aagg,              // [N, 1024] fp32
    const float* __restrict__ Ah,                // [N, 128]  fp32
    const float* __restrict__ Bw,                // [1024, 128] fp32 (W_rel[l] flattened r,i -> o)
    const float* __restrict__ Bs,                // [128, 128]  fp32 (W_self[l])
    float* __restrict__ Cout)                    // [N, 128] fp32 (repr_l)
{
  __shared__ float lds_a[128 * 68];   // [m][k] row stride 68 (16B-aligned, low conflict)
  __shared__ float lds_b[64 * 64];    // [k][n]
  const int tid = threadIdx.x;
  const int m0 = blockIdx.x * 128;
  const int n0 = blockIdx.y * 64;
  const int tx = tid & 7;    // 8 -> 8 cols each = 64
  const int ty = tid >> 3;   // 32 -> 4 rows each = 128
  float acc[4][8];
  #pragma unroll
  for (int i = 0; i < 4; ++i)
    #pragma unroll
    for (int j = 0; j < 8; ++j) acc[i][j] = 0.f;

  for (int kc = 0; kc < 1152; kc += KCH) {
    __syncthreads();
    // stage A: 128 rows x 64 cols (chunks never straddle the agg/h boundary)
    const float* Ap; size_t lda; int kb;
    if (kc < 1024) { Ap = Aagg; lda = 1024; kb = kc; }
    else           { Ap = Ah;   lda = H;    kb = kc - 1024; }
    #pragma unroll
    for (int s = 0; s < 8; ++s) {
      int f = s * 256 + tid;
      int m  = f >> 4;
      int k4 = (f & 15) << 2;
      float4 v = *(const float4*)(Ap + (size_t)(m0 + m) * lda + kb + k4);
      *(float4*)(lds_a + m * 68 + k4) = v;
    }
    // stage B: 64 rows x 64 cols
    const float* Bp = (kc < 1024) ? (Bw + (size_t)kc * H + n0)
                                  : (Bs + (size_t)(kc - 1024) * H + n0);
    #pragma unroll
    for (int s = 0; s < 4; ++s) {
      int f = s * 256 + tid;
      int kr = f >> 4;
      int n4 = (f & 15) << 2;
      float4 v = *(const float4*)(Bp + (size_t)kr * H + n4);
      *(float4*)(lds_b + kr * 64 + n4) = v;
    }
    __syncthreads();
    for (int k0 = 0; k0 < KCH; k0 += 4) {
      float areg[4][4];
      #pragma unroll
      for (int i = 0; i < 4; ++i) {
        float4 v = *(const float4*)(lds_a + (ty * 4 + i) * 68 + k0);
        areg[i][0] = v.x; areg[i][1] = v.y; areg[i][2] = v.z; areg[i][3] = v.w;
      }
      #pragma unroll
      for (int kk = 0; kk < 4; ++kk) {
        float4 b0 = *(const float4*)(lds_b + (k0 + kk) * 64 + tx * 8);
        float4 b1 = *(const float4*)(lds_b + (k0 + kk) * 64 + tx * 8 + 4);
        float breg[8] = {b0.x,b0.y,b0.z,b0.w,b1.x,b1.y,b1.z,b1.w};
        #pragma unroll
        for (int i = 0; i < 4; ++i)
          #pragma unroll
          for (int j = 0; j < 8; ++j)
            acc[i][j] = fmaf(areg[i][kk], breg[j], acc[i][j]);
      }
    }
  }
  #pragma unroll
  for (int i = 0; i < 4; ++i) {
    float4 o0, o1;
    o0.x = fmaxf(acc[i][0], 0.f); o0.y = fmaxf(acc[i][1], 0.f);
    o0.z = fmaxf(acc[i][2], 0.f); o0.w = fmaxf(acc[i][3], 0.f);
    o1.x = fmaxf(acc[i][4], 0.f); o1.y = fmaxf(acc[i][5], 0.f);
    o1.z = fmaxf(acc[i][6], 0.f); o1.w = fmaxf(acc[i][7], 0.f);
    float* d = Cout + (size_t)(m0 + ty * 4 + i) * H + n0 + tx * 8;
    *(float4*)d = o0;
    *(float4*)(d + 4) = o1;
  }
}

// ---------------- per-graph partial mean of repr: 8-way split + float atomics ----------------
__global__ void k_gmean(const float* __restrict__ repr, float* __restrict__ gmean)
{
  const int g = blockIdx.x, l = blockIdx.y, c = blockIdx.z, o = threadIdx.x;
  const int CH = NPG / 8;  // 125
  const float* base = repr + ((size_t)l * N_NODES + (size_t)g * NPG + (size_t)c * CH) * H + o;
  float s0 = 0.f, s1 = 0.f, s2 = 0.f, s3 = 0.f, s4 = 0.f;
  for (int i = 0; i < 125; i += 5) {
    s0 += base[(size_t)(i + 0) * H];
    s1 += base[(size_t)(i + 1) * H];
    s2 += base[(size_t)(i + 2) * H];
    s3 += base[(size_t)(i + 3) * H];
    s4 += base[(size_t)(i + 4) * H];
  }
  atomicAdd(&gmean[(size_t)g * (NL * H) + l * H + o], ((s0 + s1) + (s2 + s3)) + s4);
}

// ---------------- readout: proj / clusters / view attention / fc ----------------
__global__ __launch_bounds__(128) void k_final(
    const float* __restrict__ repr, const float* __restrict__ gmean,
    const int* __restrict__ gcount,
    const float* __restrict__ rel_tb, const float* __restrict__ Zn,
    const float* __restrict__ projW, const float* __restrict__ projB,
    const float* __restrict__ fcW, const float* __restrict__ fcB,
    const float* __restrict__ repSeq,
    const int* __restrict__ head_ids, const int* __restrict__ tail_ids,
    const int* __restrict__ rel_lab, float* __restrict__ out)
{
  const int b = blockIdx.x;
  const int o = threadIdx.x;   // 128
  __shared__ float gm[384], hf[384], tf[384];
  __shared__ float go[128], ho[128], t_o[128], re[128], rs[128], sv[128];
  __shared__ float lg[128], pr[128], red[128], att[3];

  const int hid = head_ids[b], tlid = tail_ids[b], rl = rel_lab[b];
  const float cinv = 1.f / (float)gcount[b];
  #pragma unroll
  for (int l = 0; l < NL; ++l) {
    gm[l * H + o] = gmean[(size_t)b * (NL * H) + l * H + o] * cinv;
    hf[l * H + o] = repr[((size_t)l * N_NODES + hid) * H + o];
    tf[l * H + o] = repr[((size_t)l * N_NODES + tlid) * H + o];
  }
  re[o] = rel_tb[rl * H + o];
  rs[o] = repSeq[b * H + o];
  __syncthreads();

  // g_out (leaky_relu 0.01), h_out, t_out = {gm,hf,tf} @ proj_W + proj_b
  float pb = projB[o];
  float sg = pb, sh = pb, st = pb;
  for (int i = 0; i < NL * H; ++i) {
    float wv = projW[i * H + o];
    sg = fmaf(gm[i], wv, sg);
    sh = fmaf(hf[i], wv, sh);
    st = fmaf(tf[i], wv, st);
  }
  go[o] = (sg > 0.f) ? sg : 0.01f * sg;
  ho[o] = sh;
  t_o[o] = st;
  __syncthreads();

  // cluster logits: threads 0..63 -> h, 64..127 -> t
  {
    const int k = o & 63;
    const float* v = (o < 64) ? ho : t_o;
    float s = 0.f;
    for (int i = 0; i < H; ++i) s = fmaf(v[i], Zn[k * H + i], s);
    lg[o] = s;
  }
  __syncthreads();
  if (o < 2) {   // softmax over 64 clusters (h and t)
    float* l0 = &lg[o * 64];
    float* p0 = &pr[o * 64];
    float mx = l0[0];
    for (int k = 1; k < 64; ++k) mx = fmaxf(mx, l0[k]);
    float sum = 0.f;
    for (int k = 0; k < 64; ++k) { float e = __expf(l0[k] - mx); p0[k] = e; sum += e; }
    float inv = 1.f / sum;
    for (int k = 0; k < 64; ++k) p0[k] *= inv;
  }
  __syncthreads();
  {
    float s1 = 0.f, s2 = 0.f;
    for (int k = 0; k < 64; ++k) {
      float z = Zn[k * H + o];
      s1 = fmaf(pr[k], z, s1);
      s2 = fmaf(pr[64 + k], z, s2);
    }
    s1 = 1.f / (1.f + __expf(-s1));
    s2 = 1.f / (1.f + __expf(-s2));
    sv[o] = s1 * s2;
  }
  __syncthreads();
  if (o == 0) {   // view attention (3 views)
    float d0 = 0.f, d1 = 0.f, d2 = 0.f;
    for (int i = 0; i < H; ++i) { d0 += re[i] * go[i]; d1 += re[i] * rs[i]; d2 += re[i] * sv[i]; }
    float mx = fmaxf(d0, fmaxf(d1, d2));
    float e0 = __expf(d0 - mx), e1 = __expf(d1 - mx), e2 = __expf(d2 - mx);
    float inv = 1.f / (e0 + e1 + e2);
    att[0] = e0 * inv; att[1] = e1 * inv; att[2] = e2 * inv;
  }
  __syncthreads();
  float va = att[0] * go[o] + att[1] * rs[o] + att[2] * sv[o];

  // g_rep = [hf(384) | tf(384) | re(128) | va(128)] . fc_W
  float p = 0.f;
  p = fmaf(hf[o],       fcW[o],       p);
  p = fmaf(hf[128 + o], fcW[128 + o], p);
  p = fmaf(hf[256 + o], fcW[256 + o], p);
  p = fmaf(tf[o],       fcW[384 + o], p);
  p = fmaf(tf[128 + o], fcW[512 + o], p);
  p = fmaf(tf[256 + o], fcW[640 + o], p);
  p = fmaf(re[o],       fcW[768 + o], p);
  p = fmaf(va,          fcW[896 + o], p);
  red[o] = p;
  __syncthreads();
  if (o == 0) {
    float s = 0.f;
    for (int i = 0; i < 128; ++i) s += red[i];
    out[b] = s + fcB[0];
  }
}

extern "C" void kernel_launch(void* const* d_in, const int* in_sizes, int n_in,
                              void* d_out, int out_size, void* d_ws, size_t ws_size,
                              hipStream_t stream) {
  const float* x        = (const float*)d_in[0];
  const float* W_rel    = (const float*)d_in[1];
  const float* W_self   = (const float*)d_in[2];
  const float* rel_tb   = (const float*)d_in[3];
  const float* Zn       = (const float*)d_in[4];
  const float* proj_W   = (const float*)d_in[5];
  const float* proj_b   = (const float*)d_in[6];
  const float* fc_W     = (const float*)d_in[7];
  const float* fc_b     = (const float*)d_in[8];
  const float* rep_seq  = (const float*)d_in[9];
  const int* src      = (const int*)d_in[10];
  const int* dst      = (const int*)d_in[11];
  const int* etype    = (const int*)d_in[12];
  const int* graph_id = (const int*)d_in[13];
  const int* head_ids = (const int*)d_in[14];
  const int* tail_ids = (const int*)d_in[15];
  const int* rel_lab  = (const int*)d_in[16];
  float* out = (float*)d_out;

  // workspace carve (~183 MB), all 16B aligned
  char* w = (char*)d_ws;
  float* agg   = (float*)w; w += (size_t)N_NODES * 1024 * 4;      // 131.07 MB
  float* repr  = (float*)w; w += (size_t)NL * N_NODES * H * 4;    //  49.15 MB
  int* row_ptr = (int*)w;   w += (size_t)32004 * 4;
  int* edge_dat= (int*)w;   w += (size_t)NEDGE * 4;
  // zero-initialized region (single memset): cursor | gcount | gmean
  char* z = w;
  int* cursor  = (int*)w;   w += (size_t)N_NODES * 4;
  int* gcount  = (int*)w;   w += (size_t)32 * 4;
  float* gmean = (float*)w; w += (size_t)BSZ * NL * H * 4;
  size_t zbytes = (size_t)(w - z);

  hipMemsetAsync(z, 0, zbytes, stream);
  k_count <<<NEDGE / 256, 256, 0, stream>>>(dst, cursor);
  k_scan  <<<1, 256, 0, stream>>>(cursor, row_ptr);
  k_fill  <<<NEDGE / 256, 256, 0, stream>>>(src, dst, etype, cursor, edge_dat);
  k_gcount<<<1, 256, 0, stream>>>(graph_id, gcount);

  for (int l = 0; l < NL; ++l) {
    const float* hp = (l == 0) ? x : (repr + (size_t)(l - 1) * N_NODES * H);
    float* hout = repr + (size_t)l * N_NODES * H;
    k_agg <<<N_NODES / 4, 256, 0, stream>>>(hp, row_ptr, edge_dat, agg);
    k_gemm<<<dim3(N_NODES / 128, 2), 256, 0, stream>>>(
        agg, hp,
        W_rel + (size_t)l * NR * H * H,
        W_self + (size_t)l * H * H,
        hout);
  }
  k_gmean<<<dim3(BSZ, NL, 8), H, 0, stream>>>(repr, gmean);
  k_final<<<BSZ, H, 0, stream>>>(repr, gmean, gcount, rel_tb, Zn, proj_W, proj_b, fc_W, fc_b,
                                 rep_seq, head_ids, tail_ids, rel_lab, out);
  (void)in_sizes; (void)n_in; (void)out_size; (void)ws_size;
}

// Round 4
// 436.623 us; speedup vs baseline: 2.2394x; 1.8907x over previous
//
#include <hip/hip_runtime.h>

#define N_NODES 32000
#define NPG     1000
#define BSZ     32
#define NEDGE   512000
#define H       128
#define NL      3
#define NR      8

typedef __attribute__((ext_vector_type(8))) short short8;
typedef __attribute__((ext_vector_type(4))) float float4v;

__device__ __forceinline__ float bf2f(unsigned short u) {
  union { unsigned int i; float f; } v;
  v.i = ((unsigned int)u) << 16;
  return v.f;
}
__device__ __forceinline__ unsigned short f2bf(float f) {
  union { float f; unsigned int i; } v;
  v.f = f;
  unsigned int x = v.i;
  return (unsigned short)((x + 0x7FFFu + ((x >> 16) & 1u)) >> 16);  // RNE
}

// ---------------- CSR build (by dst), payload = src*8 | etype ----------------
__global__ void k_count(const int* __restrict__ dst, int* __restrict__ cnt) {
  int e = blockIdx.x * blockDim.x + threadIdx.x;
  if (e < NEDGE) atomicAdd(&cnt[dst[e]], 1);
}

__global__ void k_scan(int* __restrict__ cursor, int* __restrict__ row_ptr) {
  __shared__ int ssum[256];
  __shared__ int soff[256];
  const int tid = threadIdx.x;
  const int CH = N_NODES / 256;  // 125
  const int base = tid * CH;
  int s = 0;
  for (int i = 0; i < CH; ++i) s += cursor[base + i];
  ssum[tid] = s;
  __syncthreads();
  if (tid == 0) {
    int r = 0;
    for (int i = 0; i < 256; ++i) { soff[i] = r; r += ssum[i]; }
    row_ptr[N_NODES] = r;
  }
  __syncthreads();
  int off = soff[tid];
  for (int i = 0; i < CH; ++i) {
    int c = cursor[base + i];
    row_ptr[base + i] = off;
    cursor[base + i] = off;
    off += c;
  }
}

__global__ void k_fill(const int* __restrict__ src, const int* __restrict__ dst,
                       const int* __restrict__ etype, int* __restrict__ cursor,
                       int* __restrict__ edge_dat) {
  int e = blockIdx.x * blockDim.x + threadIdx.x;
  if (e < NEDGE) {
    int p = atomicAdd(&cursor[dst[e]], 1);
    edge_dat[p] = (src[e] << 3) | etype[e];
  }
}

// run-length LDS histogram (graph_id sorted)
__global__ void k_gcount(const int* __restrict__ graph_id, int* __restrict__ gcount) {
  __shared__ int hist[BSZ];
  const int tid = threadIdx.x;  // 256
  if (tid < BSZ) hist[tid] = 0;
  __syncthreads();
  const int CH = N_NODES / 256;  // 125
  const int base = tid * CH;
  int cur = graph_id[base];
  int run = 1;
  for (int i = 1; i < CH; ++i) {
    int g = graph_id[base + i];
    if (g == cur) { ++run; }
    else { atomicAdd(&hist[cur], run); cur = g; run = 1; }
  }
  atomicAdd(&hist[cur], run);
  __syncthreads();
  if (tid < BSZ) gcount[tid] = hist[tid];
}

// ---------------- x fp32 -> h0 bf16 ----------------
__global__ void k_cvtX(const float* __restrict__ x, unsigned short* __restrict__ hb) {
  const size_t i = ((size_t)blockIdx.x * blockDim.x + threadIdx.x) * 4;
  float4 v = *(const float4*)(x + i);
  ushort4 u = { f2bf(v.x), f2bf(v.y), f2bf(v.z), f2bf(v.w) };
  *(ushort4*)(hb + i) = u;
}

// ---------------- [Wrel;Wself] fp32 -> Bt[l][n][k] bf16 (transposed) ----------------
__global__ void k_cvtB(const float* __restrict__ W_rel, const float* __restrict__ W_self,
                       unsigned short* __restrict__ Bt) {
  const int t = blockIdx.x * blockDim.x + threadIdx.x;  // 3*128*1152 total
  const int k = t % 1152;
  const int n = (t / 1152) % 128;
  const int l = t / (1152 * 128);
  float v = (k < 1024) ? W_rel[((size_t)l * 1024 + k) * 128 + n]
                       : W_self[((size_t)l * 128 + (k - 1024)) * 128 + n];
  Bt[(size_t)l * (128 * 1152) + (size_t)n * 1152 + k] = f2bf(v);
}

// ---------------- per-node gather-aggregate (bf16 in/out, fp32 accumulate) ----------------
__global__ __launch_bounds__(256) void k_agg(
    const unsigned short* __restrict__ h, const int* __restrict__ row_ptr,
    const int* __restrict__ edge_dat, unsigned short* __restrict__ agg)
{
  const int node = blockIdx.x * 4 + (threadIdx.x >> 6);
  const int lane = threadIdx.x & 63;
  const int c0 = lane * 2;
  float2 a0={0,0},a1={0,0},a2={0,0},a3={0,0},a4={0,0},a5={0,0},a6={0,0},a7={0,0};
  const int beg = row_ptr[node];
  const int end = row_ptr[node + 1];

#define ACC(vv, uu) { \
    float px = bf2f((unsigned short)((uu) & 0xffff)); \
    float py = bf2f((unsigned short)((uu) >> 16)); \
    switch ((vv) & 7) { \
      case 0: a0.x+=px; a0.y+=py; break; case 1: a1.x+=px; a1.y+=py; break; \
      case 2: a2.x+=px; a2.y+=py; break; case 3: a3.x+=px; a3.y+=py; break; \
      case 4: a4.x+=px; a4.y+=py; break; case 5: a5.x+=px; a5.y+=py; break; \
      case 6: a6.x+=px; a6.y+=py; break; case 7: a7.x+=px; a7.y+=py; break; } }

  for (int base = beg; base < end; base += 8) {
    const int cnt = end - base;
    int ed = (lane < 8 && lane < cnt) ? edge_dat[base + lane] : 0;
    if (cnt >= 8) {  // fast path: 8 row-loads in flight before any accumulate
      int vv[8]; unsigned int uu[8];
      #pragma unroll
      for (int i = 0; i < 8; ++i) {
        vv[i] = __builtin_amdgcn_readfirstlane(__shfl(ed, i));
        uu[i] = *(const unsigned int*)(h + (size_t)(vv[i] >> 3) * H + c0);
      }
      #pragma unroll
      for (int i = 0; i < 8; ++i) ACC(vv[i], uu[i]);
    } else {
      for (int i = 0; i < cnt; ++i) {
        int v = __builtin_amdgcn_readfirstlane(__shfl(ed, i));
        unsigned int u = *(const unsigned int*)(h + (size_t)(v >> 3) * H + c0);
        ACC(v, u);
      }
    }
  }
#undef ACC

  unsigned short* o = agg + (size_t)node * (NR * H) + c0;
#define ST(r, av) *(unsigned int*)(o + r * H) = (unsigned int)f2bf(av.x) | ((unsigned int)f2bf(av.y) << 16);
  ST(0, a0) ST(1, a1) ST(2, a2) ST(3, a3) ST(4, a4) ST(5, a5) ST(6, a6) ST(7, a7)
#undef ST
}

// ---------------- MFMA GEMM: relu([agg|h]_bf16 @ Bt^T) -> repr fp32 (+ h_next bf16) ----
// M=32000, K=1152, N=128. Block: 128x128 tile, 4 waves, each wave 64x64.
__global__ __launch_bounds__(256) void k_gemm_mfma(
    const unsigned short* __restrict__ Aagg,   // [N,1024] bf16
    const unsigned short* __restrict__ Ah,     // [N,128]  bf16
    const unsigned short* __restrict__ Bt,     // [128][1152] bf16
    float* __restrict__ Cout,                  // [N,128] fp32
    unsigned short* __restrict__ Hnext)        // [N,128] bf16 or nullptr
{
  __shared__ unsigned short lds_a[128 * 72];   // stride 72 ush = 144B (16B pad)
  __shared__ unsigned short lds_b[128 * 72];
  const int tid  = threadIdx.x;
  const int wave = tid >> 6, lane = tid & 63;
  const int l15 = lane & 15, quad = lane >> 4;
  const int m0 = blockIdx.x * 128;
  const int mb = (wave & 1) * 64;
  const int nb = (wave >> 1) * 64;

  float4v acc[4][4];
  #pragma unroll
  for (int i = 0; i < 4; ++i)
    #pragma unroll
    for (int j = 0; j < 4; ++j) acc[i][j] = (float4v){0.f, 0.f, 0.f, 0.f};

  for (int kc = 0; kc < 1152; kc += 64) {
    __syncthreads();
    const unsigned short* Ap; int lda, kb;
    if (kc < 1024) { Ap = Aagg; lda = 1024; kb = kc; }
    else           { Ap = Ah;   lda = 128;  kb = kc - 1024; }
    #pragma unroll
    for (int s = 0; s < 4; ++s) {
      int f  = s * 256 + tid;       // 0..1023
      int m  = f >> 3;              // 0..127
      int ko = (f & 7) * 8;         // 0..56
      *(uint4*)(lds_a + m * 72 + ko) = *(const uint4*)(Ap + (size_t)(m0 + m) * lda + kb + ko);
      *(uint4*)(lds_b + m * 72 + ko) = *(const uint4*)(Bt + (size_t)m * 1152 + kc + ko);
    }
    __syncthreads();
    #pragma unroll
    for (int ks = 0; ks < 2; ++ks) {
      const int ko = ks * 32 + quad * 8;
      short8 afr[4], bfr[4];
      #pragma unroll
      for (int i = 0; i < 4; ++i)
        afr[i] = *(const short8*)(lds_a + (mb + i * 16 + l15) * 72 + ko);
      #pragma unroll
      for (int j = 0; j < 4; ++j)
        bfr[j] = *(const short8*)(lds_b + (nb + j * 16 + l15) * 72 + ko);
      #pragma unroll
      for (int i = 0; i < 4; ++i)
        #pragma unroll
        for (int j = 0; j < 4; ++j)
          acc[i][j] = __builtin_amdgcn_mfma_f32_16x16x32_bf16(afr[i], bfr[j], acc[i][j], 0, 0, 0);
    }
  }
  // epilogue: relu, fp32 repr + bf16 h_next. D: row=quad*4+reg, col=l15.
  #pragma unroll
  for (int i = 0; i < 4; ++i)
    #pragma unroll
    for (int j = 0; j < 4; ++j)
      #pragma unroll
      for (int r = 0; r < 4; ++r) {
        int row = m0 + mb + i * 16 + quad * 4 + r;
        int col = nb + j * 16 + l15;
        float v = fmaxf(acc[i][j][r], 0.f);
        Cout[(size_t)row * H + col] = v;
        if (Hnext) Hnext[(size_t)row * H + col] = f2bf(v);
      }
}

// ---------------- per-graph partial mean (8-way split + float atomics) ----------------
__global__ void k_gmean(const float* __restrict__ repr, float* __restrict__ gmean)
{
  const int g = blockIdx.x, l = blockIdx.y, c = blockIdx.z, o = threadIdx.x;
  const int CH = NPG / 8;  // 125
  const float* base = repr + ((size_t)l * N_NODES + (size_t)g * NPG + (size_t)c * CH) * H + o;
  float s0 = 0.f, s1 = 0.f, s2 = 0.f, s3 = 0.f, s4 = 0.f;
  for (int i = 0; i < 125; i += 5) {
    s0 += base[(size_t)(i + 0) * H];
    s1 += base[(size_t)(i + 1) * H];
    s2 += base[(size_t)(i + 2) * H];
    s3 += base[(size_t)(i + 3) * H];
    s4 += base[(size_t)(i + 4) * H];
  }
  atomicAdd(&gmean[(size_t)g * (NL * H) + l * H + o], ((s0 + s1) + (s2 + s3)) + s4);
}

// ---------------- readout ----------------
__global__ __launch_bounds__(128) void k_final(
    const float* __restrict__ repr, const float* __restrict__ gmean,
    const int* __restrict__ gcount,
    const float* __restrict__ rel_tb, const float* __restrict__ Zn,
    const float* __restrict__ projW, const float* __restrict__ projB,
    const float* __restrict__ fcW, const float* __restrict__ fcB,
    const float* __restrict__ repSeq,
    const int* __restrict__ head_ids, const int* __restrict__ tail_ids,
    const int* __restrict__ rel_lab, float* __restrict__ out)
{
  const int b = blockIdx.x;
  const int o = threadIdx.x;   // 128
  __shared__ float gm[384], hf[384], tf[384];
  __shared__ float go[128], ho[128], t_o[128], re[128], rs[128], sv[128];
  __shared__ float lg[128], pr[128], red[128], att[3];

  const int hid = head_ids[b], tlid = tail_ids[b], rl = rel_lab[b];
  const float cinv = 1.f / (float)gcount[b];
  #pragma unroll
  for (int l = 0; l < NL; ++l) {
    gm[l * H + o] = gmean[(size_t)b * (NL * H) + l * H + o] * cinv;
    hf[l * H + o] = repr[((size_t)l * N_NODES + hid) * H + o];
    tf[l * H + o] = repr[((size_t)l * N_NODES + tlid) * H + o];
  }
  re[o] = rel_tb[rl * H + o];
  rs[o] = repSeq[b * H + o];
  __syncthreads();

  float pb = projB[o];
  float sg = pb, sh = pb, st = pb;
  for (int i = 0; i < NL * H; ++i) {
    float wv = projW[i * H + o];
    sg = fmaf(gm[i], wv, sg);
    sh = fmaf(hf[i], wv, sh);
    st = fmaf(tf[i], wv, st);
  }
  go[o] = (sg > 0.f) ? sg : 0.01f * sg;
  ho[o] = sh;
  t_o[o] = st;
  __syncthreads();

  {
    const int k = o & 63;
    const float* v = (o < 64) ? ho : t_o;
    float s = 0.f;
    for (int i = 0; i < H; ++i) s = fmaf(v[i], Zn[k * H + i], s);
    lg[o] = s;
  }
  __syncthreads();
  if (o < 2) {
    float* l0 = &lg[o * 64];
    float* p0 = &pr[o * 64];
    float mx = l0[0];
    for (int k = 1; k < 64; ++k) mx = fmaxf(mx, l0[k]);
    float sum = 0.f;
    for (int k = 0; k < 64; ++k) { float e = __expf(l0[k] - mx); p0[k] = e; sum += e; }
    float inv = 1.f / sum;
    for (int k = 0; k < 64; ++k) p0[k] *= inv;
  }
  __syncthreads();
  {
    float s1 = 0.f, s2 = 0.f;
    for (int k = 0; k < 64; ++k) {
      float z = Zn[k * H + o];
      s1 = fmaf(pr[k], z, s1);
      s2 = fmaf(pr[64 + k], z, s2);
    }
    s1 = 1.f / (1.f + __expf(-s1));
    s2 = 1.f / (1.f + __expf(-s2));
    sv[o] = s1 * s2;
  }
  __syncthreads();
  if (o == 0) {
    float d0 = 0.f, d1 = 0.f, d2 = 0.f;
    for (int i = 0; i < H; ++i) { d0 += re[i] * go[i]; d1 += re[i] * rs[i]; d2 += re[i] * sv[i]; }
    float mx = fmaxf(d0, fmaxf(d1, d2));
    float e0 = __expf(d0 - mx), e1 = __expf(d1 - mx), e2 = __expf(d2 - mx);
    float inv = 1.f / (e0 + e1 + e2);
    att[0] = e0 * inv; att[1] = e1 * inv; att[2] = e2 * inv;
  }
  __syncthreads();
  float va = att[0] * go[o] + att[1] * rs[o] + att[2] * sv[o];

  float p = 0.f;
  p = fmaf(hf[o],       fcW[o],       p);
  p = fmaf(hf[128 + o], fcW[128 + o], p);
  p = fmaf(hf[256 + o], fcW[256 + o], p);
  p = fmaf(tf[o],       fcW[384 + o], p);
  p = fmaf(tf[128 + o], fcW[512 + o], p);
  p = fmaf(tf[256 + o], fcW[640 + o], p);
  p = fmaf(re[o],       fcW[768 + o], p);
  p = fmaf(va,          fcW[896 + o], p);
  red[o] = p;
  __syncthreads();
  if (o == 0) {
    float s = 0.f;
    for (int i = 0; i < 128; ++i) s += red[i];
    out[b] = s + fcB[0];
  }
}

extern "C" void kernel_launch(void* const* d_in, const int* in_sizes, int n_in,
                              void* d_out, int out_size, void* d_ws, size_t ws_size,
                              hipStream_t stream) {
  const float* x        = (const float*)d_in[0];
  const float* W_rel    = (const float*)d_in[1];
  const float* W_self   = (const float*)d_in[2];
  const float* rel_tb   = (const float*)d_in[3];
  const float* Zn       = (const float*)d_in[4];
  const float* proj_W   = (const float*)d_in[5];
  const float* proj_b   = (const float*)d_in[6];
  const float* fc_W     = (const float*)d_in[7];
  const float* fc_b     = (const float*)d_in[8];
  const float* rep_seq  = (const float*)d_in[9];
  const int* src      = (const int*)d_in[10];
  const int* dst      = (const int*)d_in[11];
  const int* etype    = (const int*)d_in[12];
  const int* graph_id = (const int*)d_in[13];
  const int* head_ids = (const int*)d_in[14];
  const int* tail_ids = (const int*)d_in[15];
  const int* rel_lab  = (const int*)d_in[16];
  float* out = (float*)d_out;

  // workspace carve (~142 MB), all 16B aligned
  char* w = (char*)d_ws;
  unsigned short* agg_bf = (unsigned short*)w; w += (size_t)N_NODES * 1024 * 2;  // 65.5 MB
  unsigned short* hb     = (unsigned short*)w; w += (size_t)NL * N_NODES * H * 2; // 24.6 MB
  float* repr  = (float*)w; w += (size_t)NL * N_NODES * H * 4;                    // 49.2 MB
  unsigned short* Bt = (unsigned short*)w; w += (size_t)NL * 128 * 1152 * 2;      // 0.88 MB
  int* row_ptr = (int*)w;   w += (size_t)32004 * 4;
  int* edge_dat= (int*)w;   w += (size_t)NEDGE * 4;
  // zero region: cursor | gcount | gmean
  char* z = w;
  int* cursor  = (int*)w;   w += (size_t)N_NODES * 4;
  int* gcount  = (int*)w;   w += (size_t)32 * 4;
  float* gmean = (float*)w; w += (size_t)BSZ * NL * H * 4;
  size_t zbytes = (size_t)(w - z);

  hipMemsetAsync(z, 0, zbytes, stream);
  k_count <<<NEDGE / 256, 256, 0, stream>>>(dst, cursor);
  k_scan  <<<1, 256, 0, stream>>>(cursor, row_ptr);
  k_fill  <<<NEDGE / 256, 256, 0, stream>>>(src, dst, etype, cursor, edge_dat);
  k_gcount<<<1, 256, 0, stream>>>(graph_id, gcount);
  k_cvtX  <<<(N_NODES * H) / (256 * 4), 256, 0, stream>>>(x, hb);
  k_cvtB  <<<(NL * 128 * 1152) / 256, 256, 0, stream>>>(W_rel, W_self, Bt);

  for (int l = 0; l < NL; ++l) {
    const unsigned short* hp = hb + (size_t)l * N_NODES * H;
    unsigned short* hn = (l < NL - 1) ? (unsigned short*)(hb + (size_t)(l + 1) * N_NODES * H)
                                      : (unsigned short*)nullptr;
    float* hout = repr + (size_t)l * N_NODES * H;
    k_agg <<<N_NODES / 4, 256, 0, stream>>>(hp, row_ptr, edge_dat, agg_bf);
    k_gemm_mfma<<<N_NODES / 128, 256, 0, stream>>>(
        agg_bf, hp, Bt + (size_t)l * 128 * 1152, hout, hn);
  }
  k_gmean<<<dim3(BSZ, NL, 8), H, 0, stream>>>(repr, gmean);
  k_final<<<BSZ, H, 0, stream>>>(repr, gmean, gcount, rel_tb, Zn, proj_W, proj_b, fc_W, fc_b,
                                 rep_seq, head_ids, tail_ids, rel_lab, out);
  (void)in_sizes; (void)n_in; (void)out_size; (void)ws_size;
}

// Round 5
// 395.869 us; speedup vs baseline: 2.4699x; 1.1029x over previous
//
#include <hip/hip_runtime.h>

#define N_NODES 32000
#define NPG     1000
#define BSZ     32
#define NEDGE   512000
#define H       128
#define NL      3
#define NR      8

typedef __attribute__((ext_vector_type(8))) short short8;
typedef __attribute__((ext_vector_type(4))) float float4v;

__device__ __forceinline__ float bf2f(unsigned short u) {
  union { unsigned int i; float f; } v;
  v.i = ((unsigned int)u) << 16;
  return v.f;
}
__device__ __forceinline__ unsigned short f2bf(float f) {
  union { float f; unsigned int i; } v;
  v.f = f;
  unsigned int x = v.i;
  return (unsigned short)((x + 0x7FFFu + ((x >> 16) & 1u)) >> 16);  // RNE
}

// ---------------- CSR build (by dst), payload = src*8 | etype ----------------
__global__ void k_count(const int* __restrict__ dst, int* __restrict__ cnt) {
  int e = blockIdx.x * blockDim.x + threadIdx.x;
  if (e < NEDGE) atomicAdd(&cnt[dst[e]], 1);
}

__global__ void k_scan(int* __restrict__ cursor, int* __restrict__ row_ptr) {
  __shared__ int ssum[256];
  __shared__ int soff[256];
  const int tid = threadIdx.x;
  const int CH = N_NODES / 256;  // 125
  const int base = tid * CH;
  int s = 0;
  for (int i = 0; i < CH; ++i) s += cursor[base + i];
  ssum[tid] = s;
  __syncthreads();
  if (tid == 0) {
    int r = 0;
    for (int i = 0; i < 256; ++i) { soff[i] = r; r += ssum[i]; }
    row_ptr[N_NODES] = r;
  }
  __syncthreads();
  int off = soff[tid];
  for (int i = 0; i < CH; ++i) {
    int c = cursor[base + i];
    row_ptr[base + i] = off;
    cursor[base + i] = off;
    off += c;
  }
}

__global__ void k_fill(const int* __restrict__ src, const int* __restrict__ dst,
                       const int* __restrict__ etype, int* __restrict__ cursor,
                       int* __restrict__ edge_dat) {
  int e = blockIdx.x * blockDim.x + threadIdx.x;
  if (e < NEDGE) {
    int p = atomicAdd(&cursor[dst[e]], 1);
    edge_dat[p] = (src[e] << 3) | etype[e];
  }
}

// parallel histogram: 125 blocks, per-block LDS hist, <=2 hot bins/block
__global__ void k_gcount(const int* __restrict__ graph_id, int* __restrict__ gcount) {
  __shared__ int hist[BSZ];
  const int t = threadIdx.x;  // 256
  if (t < BSZ) hist[t] = 0;
  __syncthreads();
  const int n = blockIdx.x * 256 + t;
  if (n < N_NODES) atomicAdd(&hist[graph_id[n]], 1);
  __syncthreads();
  if (t < BSZ) { int v = hist[t]; if (v) atomicAdd(&gcount[t], v); }
}

// ---------------- x fp32 -> h0 bf16 ----------------
__global__ void k_cvtX(const float* __restrict__ x, unsigned short* __restrict__ hb) {
  const size_t i = ((size_t)blockIdx.x * blockDim.x + threadIdx.x) * 4;
  float4 v = *(const float4*)(x + i);
  ushort4 u = { f2bf(v.x), f2bf(v.y), f2bf(v.z), f2bf(v.w) };
  *(ushort4*)(hb + i) = u;
}

// ---------------- [Wrel;Wself] fp32 -> Bt[l][n][k] bf16 (transposed) ----------------
__global__ void k_cvtB(const float* __restrict__ W_rel, const float* __restrict__ W_self,
                       unsigned short* __restrict__ Bt) {
  const int t = blockIdx.x * blockDim.x + threadIdx.x;  // 3*128*1152 total
  const int k = t % 1152;
  const int n = (t / 1152) % 128;
  const int l = t / (1152 * 128);
  float v = (k < 1024) ? W_rel[((size_t)l * 1024 + k) * 128 + n]
                       : W_self[((size_t)l * 128 + (k - 1024)) * 128 + n];
  Bt[(size_t)l * (128 * 1152) + (size_t)n * 1152 + k] = f2bf(v);
}

// ---------------- per-node gather-aggregate (bf16 in/out, fp32 accumulate) ----------------
__global__ __launch_bounds__(256) void k_agg(
    const unsigned short* __restrict__ h, const int* __restrict__ row_ptr,
    const int* __restrict__ edge_dat, unsigned short* __restrict__ agg)
{
  const int node = blockIdx.x * 4 + (threadIdx.x >> 6);
  const int lane = threadIdx.x & 63;
  const int c0 = lane * 2;
  float2 a0={0,0},a1={0,0},a2={0,0},a3={0,0},a4={0,0},a5={0,0},a6={0,0},a7={0,0};
  const int beg = row_ptr[node];
  const int end = row_ptr[node + 1];

#define ACC(vv, uu) { \
    float px = bf2f((unsigned short)((uu) & 0xffff)); \
    float py = bf2f((unsigned short)((uu) >> 16)); \
    switch ((vv) & 7) { \
      case 0: a0.x+=px; a0.y+=py; break; case 1: a1.x+=px; a1.y+=py; break; \
      case 2: a2.x+=px; a2.y+=py; break; case 3: a3.x+=px; a3.y+=py; break; \
      case 4: a4.x+=px; a4.y+=py; break; case 5: a5.x+=px; a5.y+=py; break; \
      case 6: a6.x+=px; a6.y+=py; break; case 7: a7.x+=px; a7.y+=py; break; } }

  for (int base = beg; base < end; base += 8) {
    const int cnt = end - base;
    int ed = (lane < 8 && lane < cnt) ? edge_dat[base + lane] : 0;
    if (cnt >= 8) {  // fast path: 8 row-loads in flight before any accumulate
      int vv[8]; unsigned int uu[8];
      #pragma unroll
      for (int i = 0; i < 8; ++i) {
        vv[i] = __builtin_amdgcn_readfirstlane(__shfl(ed, i));
        uu[i] = *(const unsigned int*)(h + (size_t)(vv[i] >> 3) * H + c0);
      }
      #pragma unroll
      for (int i = 0; i < 8; ++i) ACC(vv[i], uu[i]);
    } else {
      for (int i = 0; i < cnt; ++i) {
        int v = __builtin_amdgcn_readfirstlane(__shfl(ed, i));
        unsigned int u = *(const unsigned int*)(h + (size_t)(v >> 3) * H + c0);
        ACC(v, u);
      }
    }
  }
#undef ACC

  unsigned short* o = agg + (size_t)node * (NR * H) + c0;
#define ST(r, av) *(unsigned int*)(o + r * H) = (unsigned int)f2bf(av.x) | ((unsigned int)f2bf(av.y) << 16);
  ST(0, a0) ST(1, a1) ST(2, a2) ST(3, a3) ST(4, a4) ST(5, a5) ST(6, a6) ST(7, a7)
#undef ST
}

// ---------------- MFMA GEMM: relu([agg|h]_bf16 @ Bt^T) -> h_next bf16 ----------------
// M=32000, K=1152, N=128. Block: 128x128 tile, 4 waves, each wave 64x64.
__global__ __launch_bounds__(256) void k_gemm_mfma(
    const unsigned short* __restrict__ Aagg,   // [N,1024] bf16
    const unsigned short* __restrict__ Ah,     // [N,128]  bf16
    const unsigned short* __restrict__ Bt,     // [128][1152] bf16
    unsigned short* __restrict__ Hnext)        // [N,128] bf16
{
  __shared__ unsigned short lds_a[128 * 72];   // stride 72 ush = 144B (16B pad)
  __shared__ unsigned short lds_b[128 * 72];
  const int tid  = threadIdx.x;
  const int wave = tid >> 6, lane = tid & 63;
  const int l15 = lane & 15, quad = lane >> 4;
  const int m0 = blockIdx.x * 128;
  const int mb = (wave & 1) * 64;
  const int nb = (wave >> 1) * 64;

  float4v acc[4][4];
  #pragma unroll
  for (int i = 0; i < 4; ++i)
    #pragma unroll
    for (int j = 0; j < 4; ++j) acc[i][j] = (float4v){0.f, 0.f, 0.f, 0.f};

  for (int kc = 0; kc < 1152; kc += 64) {
    __syncthreads();
    const unsigned short* Ap; int lda, kb;
    if (kc < 1024) { Ap = Aagg; lda = 1024; kb = kc; }
    else           { Ap = Ah;   lda = 128;  kb = kc - 1024; }
    #pragma unroll
    for (int s = 0; s < 4; ++s) {
      int f  = s * 256 + tid;       // 0..1023
      int m  = f >> 3;              // 0..127
      int ko = (f & 7) * 8;         // 0..56
      *(uint4*)(lds_a + m * 72 + ko) = *(const uint4*)(Ap + (size_t)(m0 + m) * lda + kb + ko);
      *(uint4*)(lds_b + m * 72 + ko) = *(const uint4*)(Bt + (size_t)m * 1152 + kc + ko);
    }
    __syncthreads();
    #pragma unroll
    for (int ks = 0; ks < 2; ++ks) {
      const int ko = ks * 32 + quad * 8;
      short8 afr[4], bfr[4];
      #pragma unroll
      for (int i = 0; i < 4; ++i)
        afr[i] = *(const short8*)(lds_a + (mb + i * 16 + l15) * 72 + ko);
      #pragma unroll
      for (int j = 0; j < 4; ++j)
        bfr[j] = *(const short8*)(lds_b + (nb + j * 16 + l15) * 72 + ko);
      #pragma unroll
      for (int i = 0; i < 4; ++i)
        #pragma unroll
        for (int j = 0; j < 4; ++j)
          acc[i][j] = __builtin_amdgcn_mfma_f32_16x16x32_bf16(afr[i], bfr[j], acc[i][j], 0, 0, 0);
    }
  }
  // epilogue: relu -> bf16 h_next. D: row=quad*4+reg, col=l15.
  #pragma unroll
  for (int i = 0; i < 4; ++i)
    #pragma unroll
    for (int j = 0; j < 4; ++j)
      #pragma unroll
      for (int r = 0; r < 4; ++r) {
        int row = m0 + mb + i * 16 + quad * 4 + r;
        int col = nb + j * 16 + l15;
        Hnext[(size_t)row * H + col] = f2bf(fmaxf(acc[i][j][r], 0.f));
      }
}

// ---------------- per-graph partial mean from bf16 h (8-way split + float atomics) ----
// 64 threads: thread t handles cols 2t,2t+1 via uint loads (coalesced 256B/row)
__global__ void k_gmean(const unsigned short* __restrict__ hb, float* __restrict__ gmean)
{
  const int g = blockIdx.x, l = blockIdx.y, c = blockIdx.z, t = threadIdx.x;  // 64
  const unsigned short* base =
      hb + ((size_t)(l + 1) * N_NODES + (size_t)g * NPG + (size_t)c * (NPG / 8)) * H + t * 2;
  float sx = 0.f, sy = 0.f;
  for (int i = 0; i < 125; ++i) {
    unsigned int u = *(const unsigned int*)(base + (size_t)i * H);
    sx += bf2f((unsigned short)(u & 0xffff));
    sy += bf2f((unsigned short)(u >> 16));
  }
  float* gp = gmean + (size_t)g * (NL * H) + l * H + t * 2;
  atomicAdd(gp, sx);
  atomicAdd(gp + 1, sy);
}

// ---------------- readout ----------------
__global__ __launch_bounds__(128) void k_final(
    const unsigned short* __restrict__ hb, const float* __restrict__ gmean,
    const int* __restrict__ gcount,
    const float* __restrict__ rel_tb, const float* __restrict__ Zn,
    const float* __restrict__ projW, const float* __restrict__ projB,
    const float* __restrict__ fcW, const float* __restrict__ fcB,
    const float* __restrict__ repSeq,
    const int* __restrict__ head_ids, const int* __restrict__ tail_ids,
    const int* __restrict__ rel_lab, float* __restrict__ out)
{
  const int b = blockIdx.x;
  const int o = threadIdx.x;   // 128
  __shared__ float gm[384], hf[384], tf[384];
  __shared__ float go[128], ho[128], t_o[128], re[128], rs[128], sv[128];
  __shared__ float lg[128], pr[128], red[128], att[3];

  const int hid = head_ids[b], tlid = tail_ids[b], rl = rel_lab[b];
  const float cinv = 1.f / (float)gcount[b];
  #pragma unroll
  for (int l = 0; l < NL; ++l) {
    gm[l * H + o] = gmean[(size_t)b * (NL * H) + l * H + o] * cinv;
    hf[l * H + o] = bf2f(hb[((size_t)(l + 1) * N_NODES + hid) * H + o]);
    tf[l * H + o] = bf2f(hb[((size_t)(l + 1) * N_NODES + tlid) * H + o]);
  }
  re[o] = rel_tb[rl * H + o];
  rs[o] = repSeq[b * H + o];
  __syncthreads();

  float pb = projB[o];
  float sg = pb, sh = pb, st = pb;
  for (int i = 0; i < NL * H; ++i) {
    float wv = projW[i * H + o];
    sg = fmaf(gm[i], wv, sg);
    sh = fmaf(hf[i], wv, sh);
    st = fmaf(tf[i], wv, st);
  }
  go[o] = (sg > 0.f) ? sg : 0.01f * sg;
  ho[o] = sh;
  t_o[o] = st;
  __syncthreads();

  {
    const int k = o & 63;
    const float* v = (o < 64) ? ho : t_o;
    float s = 0.f;
    for (int i = 0; i < H; ++i) s = fmaf(v[i], Zn[k * H + i], s);
    lg[o] = s;
  }
  __syncthreads();
  if (o < 2) {
    float* l0 = &lg[o * 64];
    float* p0 = &pr[o * 64];
    float mx = l0[0];
    for (int k = 1; k < 64; ++k) mx = fmaxf(mx, l0[k]);
    float sum = 0.f;
    for (int k = 0; k < 64; ++k) { float e = __expf(l0[k] - mx); p0[k] = e; sum += e; }
    float inv = 1.f / sum;
    for (int k = 0; k < 64; ++k) p0[k] *= inv;
  }
  __syncthreads();
  {
    float s1 = 0.f, s2 = 0.f;
    for (int k = 0; k < 64; ++k) {
      float z = Zn[k * H + o];
      s1 = fmaf(pr[k], z, s1);
      s2 = fmaf(pr[64 + k], z, s2);
    }
    s1 = 1.f / (1.f + __expf(-s1));
    s2 = 1.f / (1.f + __expf(-s2));
    sv[o] = s1 * s2;
  }
  __syncthreads();
  if (o == 0) {
    float d0 = 0.f, d1 = 0.f, d2 = 0.f;
    for (int i = 0; i < H; ++i) { d0 += re[i] * go[i]; d1 += re[i] * rs[i]; d2 += re[i] * sv[i]; }
    float mx = fmaxf(d0, fmaxf(d1, d2));
    float e0 = __expf(d0 - mx), e1 = __expf(d1 - mx), e2 = __expf(d2 - mx);
    float inv = 1.f / (e0 + e1 + e2);
    att[0] = e0 * inv; att[1] = e1 * inv; att[2] = e2 * inv;
  }
  __syncthreads();
  float va = att[0] * go[o] + att[1] * rs[o] + att[2] * sv[o];

  float p = 0.f;
  p = fmaf(hf[o],       fcW[o],       p);
  p = fmaf(hf[128 + o], fcW[128 + o], p);
  p = fmaf(hf[256 + o], fcW[256 + o], p);
  p = fmaf(tf[o],       fcW[384 + o], p);
  p = fmaf(tf[128 + o], fcW[512 + o], p);
  p = fmaf(tf[256 + o], fcW[640 + o], p);
  p = fmaf(re[o],       fcW[768 + o], p);
  p = fmaf(va,          fcW[896 + o], p);
  red[o] = p;
  __syncthreads();
  if (o == 0) {
    float s = 0.f;
    for (int i = 0; i < 128; ++i) s += red[i];
    out[b] = s + fcB[0];
  }
}

extern "C" void kernel_launch(void* const* d_in, const int* in_sizes, int n_in,
                              void* d_out, int out_size, void* d_ws, size_t ws_size,
                              hipStream_t stream) {
  const float* x        = (const float*)d_in[0];
  const float* W_rel    = (const float*)d_in[1];
  const float* W_self   = (const float*)d_in[2];
  const float* rel_tb   = (const float*)d_in[3];
  const float* Zn       = (const float*)d_in[4];
  const float* proj_W   = (const float*)d_in[5];
  const float* proj_b   = (const float*)d_in[6];
  const float* fc_W     = (const float*)d_in[7];
  const float* fc_b     = (const float*)d_in[8];
  const float* rep_seq  = (const float*)d_in[9];
  const int* src      = (const int*)d_in[10];
  const int* dst      = (const int*)d_in[11];
  const int* etype    = (const int*)d_in[12];
  const int* graph_id = (const int*)d_in[13];
  const int* head_ids = (const int*)d_in[14];
  const int* tail_ids = (const int*)d_in[15];
  const int* rel_lab  = (const int*)d_in[16];
  float* out = (float*)d_out;

  // workspace carve (~103 MB), all 16B aligned
  char* w = (char*)d_ws;
  unsigned short* agg_bf = (unsigned short*)w; w += (size_t)N_NODES * 1024 * 2;        // 65.5 MB
  unsigned short* hb     = (unsigned short*)w; w += (size_t)(NL + 1) * N_NODES * H * 2; // 32.8 MB (h0..h3)
  unsigned short* Bt = (unsigned short*)w; w += (size_t)NL * 128 * 1152 * 2;            // 0.88 MB
  int* row_ptr = (int*)w;   w += (size_t)32004 * 4;
  int* edge_dat= (int*)w;   w += (size_t)NEDGE * 4;
  // zero region: cursor | gcount | gmean
  char* z = w;
  int* cursor  = (int*)w;   w += (size_t)N_NODES * 4;
  int* gcount  = (int*)w;   w += (size_t)32 * 4;
  float* gmean = (float*)w; w += (size_t)BSZ * NL * H * 4;
  size_t zbytes = (size_t)(w - z);

  hipMemsetAsync(z, 0, zbytes, stream);
  k_count <<<NEDGE / 256, 256, 0, stream>>>(dst, cursor);
  k_scan  <<<1, 256, 0, stream>>>(cursor, row_ptr);
  k_fill  <<<NEDGE / 256, 256, 0, stream>>>(src, dst, etype, cursor, edge_dat);
  k_gcount<<<(N_NODES + 255) / 256, 256, 0, stream>>>(graph_id, gcount);
  k_cvtX  <<<(N_NODES * H) / (256 * 4), 256, 0, stream>>>(x, hb);
  k_cvtB  <<<(NL * 128 * 1152) / 256, 256, 0, stream>>>(W_rel, W_self, Bt);

  for (int l = 0; l < NL; ++l) {
    const unsigned short* hp = hb + (size_t)l * N_NODES * H;
    unsigned short* hn = hb + (size_t)(l + 1) * N_NODES * H;
    k_agg <<<N_NODES / 4, 256, 0, stream>>>(hp, row_ptr, edge_dat, agg_bf);
    k_gemm_mfma<<<N_NODES / 128, 256, 0, stream>>>(
        agg_bf, hp, Bt + (size_t)l * 128 * 1152, hn);
  }
  k_gmean<<<dim3(BSZ, NL, 8), 64, 0, stream>>>(hb, gmean);
  k_final<<<BSZ, H, 0, stream>>>(hb, gmean, gcount, rel_tb, Zn, proj_W, proj_b, fc_W, fc_b,
                                 rep_seq, head_ids, tail_ids, rel_lab, out);
  (void)in_sizes; (void)n_in; (void)out_size; (void)ws_size;
}

// Round 6
// 384.890 us; speedup vs baseline: 2.5404x; 1.0285x over previous
//
#include <hip/hip_runtime.h>

#define N_NODES 32000
#define NPG     1000
#define BSZ     32
#define NEDGE   512000
#define H       128
#define NL      3
#define NR      8
#define NW      1152   // 8*128 rel cols + 128 self cols

typedef __attribute__((ext_vector_type(8))) short short8;
typedef __attribute__((ext_vector_type(4))) float float4v;

__device__ __forceinline__ float bf2f(unsigned short u) {
  union { unsigned int i; float f; } v;
  v.i = ((unsigned int)u) << 16;
  return v.f;
}
__device__ __forceinline__ unsigned short f2bf(float f) {
  union { float f; unsigned int i; } v;
  v.f = f;
  unsigned int x = v.i;
  return (unsigned short)((x + 0x7FFFu + ((x >> 16) & 1u)) >> 16);  // RNE
}

// ---------------- CSR build (by dst), payload = src*1152 + etype*128 ----------------
__global__ void k_count(const int* __restrict__ dst, int* __restrict__ cnt) {
  int e = blockIdx.x * blockDim.x + threadIdx.x;
  if (e < NEDGE) atomicAdd(&cnt[dst[e]], 1);
}

__global__ void k_scan(int* __restrict__ cursor, int* __restrict__ row_ptr) {
  __shared__ int ssum[256];
  __shared__ int soff[256];
  const int tid = threadIdx.x;
  const int CH = N_NODES / 256;  // 125
  const int base = tid * CH;
  int s = 0;
  for (int i = 0; i < CH; ++i) s += cursor[base + i];
  ssum[tid] = s;
  __syncthreads();
  if (tid == 0) {
    int r = 0;
    for (int i = 0; i < 256; ++i) { soff[i] = r; r += ssum[i]; }
    row_ptr[N_NODES] = r;
  }
  __syncthreads();
  int off = soff[tid];
  for (int i = 0; i < CH; ++i) {
    int c = cursor[base + i];
    row_ptr[base + i] = off;
    cursor[base + i] = off;
    off += c;
  }
}

__global__ void k_fill(const int* __restrict__ src, const int* __restrict__ dst,
                       const int* __restrict__ etype, int* __restrict__ cursor,
                       int* __restrict__ edge_off) {
  int e = blockIdx.x * blockDim.x + threadIdx.x;
  if (e < NEDGE) {
    int p = atomicAdd(&cursor[dst[e]], 1);
    edge_off[p] = src[e] * NW + etype[e] * H;   // element offset into G
  }
}

// parallel histogram: per-block LDS hist, <=2 hot bins/block
__global__ void k_gcount(const int* __restrict__ graph_id, int* __restrict__ gcount) {
  __shared__ int hist[BSZ];
  const int t = threadIdx.x;  // 256
  if (t < BSZ) hist[t] = 0;
  __syncthreads();
  const int n = blockIdx.x * 256 + t;
  if (n < N_NODES) atomicAdd(&hist[graph_id[n]], 1);
  __syncthreads();
  if (t < BSZ) { int v = hist[t]; if (v) atomicAdd(&gcount[t], v); }
}

// ---------------- x fp32 -> h0 bf16 ----------------
__global__ void k_cvtX(const float* __restrict__ x, unsigned short* __restrict__ hb) {
  const size_t i = ((size_t)blockIdx.x * blockDim.x + threadIdx.x) * 4;
  float4 v = *(const float4*)(x + i);
  ushort4 u = { f2bf(v.x), f2bf(v.y), f2bf(v.z), f2bf(v.w) };
  *(ushort4*)(hb + i) = u;
}

// ---------------- weights -> Bt9[l][n=0..1151][k=0..127] bf16 (transposed) ----------------
// n<1024: Bt9[n][k] = W_rel[l, n>>7, k, n&127];  n>=1024: Bt9[n][k] = W_self[l, k, n-1024]
__global__ void k_cvtB(const float* __restrict__ W_rel, const float* __restrict__ W_self,
                       unsigned short* __restrict__ Bt) {
  const int t = blockIdx.x * blockDim.x + threadIdx.x;  // 3*1152*128
  const int k = t & 127;
  const int n = (t >> 7) % NW;
  const int l = t / (NW * H);
  float v = (n < 1024) ? W_rel[(((size_t)l * NR + (n >> 7)) * H + k) * H + (n & 127)]
                       : W_self[((size_t)l * H + k) * H + (n - 1024)];
  Bt[(size_t)l * (NW * H) + (size_t)n * H + k] = f2bf(v);
}

// ---------------- GEMM9: G = h @ [Wrel(8) | Wself]  (M=32000, K=128, N=1152) --------
// 128x128 tile, 4 waves of 64x64, K staged once. Epilogue repacks via LDS for uint4 stores.
__global__ __launch_bounds__(256) void k_gemm9(
    const unsigned short* __restrict__ Ah,   // [32000,128] bf16
    const unsigned short* __restrict__ Bt,   // [1152,128]  bf16
    unsigned short* __restrict__ G)          // [32000,1152] bf16
{
  __shared__ unsigned short lds_a[128 * 136];   // 272B row stride (step 4 banks, measured-clean)
  __shared__ unsigned short lds_b[128 * 136];
  const int tid  = threadIdx.x;
  const int wave = tid >> 6, lane = tid & 63;
  const int l15 = lane & 15, quad = lane >> 4;
  const int m0 = blockIdx.x * 128;
  const int n0 = blockIdx.y * 128;
  const int mb = (wave & 1) * 64;
  const int nb = (wave >> 1) * 64;

  #pragma unroll
  for (int s = 0; s < 8; ++s) {
    int f  = s * 256 + tid;   // 0..2047
    int m  = f >> 4;          // 0..127
    int ko = (f & 15) * 8;    // 0..120
    *(uint4*)(lds_a + m * 136 + ko) = *(const uint4*)(Ah + (size_t)(m0 + m) * H + ko);
    *(uint4*)(lds_b + m * 136 + ko) = *(const uint4*)(Bt + (size_t)(n0 + m) * H + ko);
  }
  __syncthreads();

  float4v acc[4][4];
  #pragma unroll
  for (int i = 0; i < 4; ++i)
    #pragma unroll
    for (int j = 0; j < 4; ++j) acc[i][j] = (float4v){0.f, 0.f, 0.f, 0.f};

  #pragma unroll
  for (int ks = 0; ks < 4; ++ks) {
    const int ko = ks * 32 + quad * 8;
    short8 afr[4], bfr[4];
    #pragma unroll
    for (int i = 0; i < 4; ++i)
      afr[i] = *(const short8*)(lds_a + (mb + i * 16 + l15) * 136 + ko);
    #pragma unroll
    for (int j = 0; j < 4; ++j)
      bfr[j] = *(const short8*)(lds_b + (nb + j * 16 + l15) * 136 + ko);
    #pragma unroll
    for (int i = 0; i < 4; ++i)
      #pragma unroll
      for (int j = 0; j < 4; ++j)
        acc[i][j] = __builtin_amdgcn_mfma_f32_16x16x32_bf16(afr[i], bfr[j], acc[i][j], 0, 0, 0);
  }

  // repack: acc -> lds_a (bf16), then coalesced uint4 stores. D: row=quad*4+r, col=l15.
  __syncthreads();
  #pragma unroll
  for (int i = 0; i < 4; ++i)
    #pragma unroll
    for (int j = 0; j < 4; ++j)
      #pragma unroll
      for (int r = 0; r < 4; ++r)
        lds_a[(mb + i * 16 + quad * 4 + r) * 136 + nb + j * 16 + l15] = f2bf(acc[i][j][r]);
  __syncthreads();
  #pragma unroll
  for (int s = 0; s < 8; ++s) {
    int f  = s * 256 + tid;
    int m  = f >> 4;
    int ko = (f & 15) * 8;
    *(uint4*)(G + (size_t)(m0 + m) * NW + n0 + ko) = *(const uint4*)(lds_a + m * 136 + ko);
  }
}

// ---------------- edge gather: h_next[n] = relu(G[n,1024:] + sum_e G[edge_off[e], :128]) ----
__global__ __launch_bounds__(256) void k_gather(
    const unsigned short* __restrict__ G, const int* __restrict__ row_ptr,
    const int* __restrict__ edge_off, unsigned short* __restrict__ Hnext)
{
  const int node = blockIdx.x * 4 + (threadIdx.x >> 6);
  const int lane = threadIdx.x & 63;
  const int c0 = lane * 2;
  const int beg = row_ptr[node];
  const int end = row_ptr[node + 1];
  float sx, sy;
  {
    unsigned int u = *(const unsigned int*)(G + (size_t)node * NW + 1024 + c0);
    sx = bf2f((unsigned short)(u & 0xffff));
    sy = bf2f((unsigned short)(u >> 16));
  }
  int e = beg;
  for (; e + 8 <= end; e += 8) {
    int of[8]; unsigned int u[8];
    #pragma unroll
    for (int i = 0; i < 8; ++i) of[i] = edge_off[e + i];          // broadcast loads
    #pragma unroll
    for (int i = 0; i < 8; ++i)
      u[i] = *(const unsigned int*)(G + (size_t)of[i] + c0);      // 8 gathers in flight
    #pragma unroll
    for (int i = 0; i < 8; ++i) {
      sx += bf2f((unsigned short)(u[i] & 0xffff));
      sy += bf2f((unsigned short)(u[i] >> 16));
    }
  }
  for (; e < end; ++e) {
    int of = edge_off[e];
    unsigned int u = *(const unsigned int*)(G + (size_t)of + c0);
    sx += bf2f((unsigned short)(u & 0xffff));
    sy += bf2f((unsigned short)(u >> 16));
  }
  sx = fmaxf(sx, 0.f);
  sy = fmaxf(sy, 0.f);
  *(unsigned int*)(Hnext + (size_t)node * H + c0) =
      (unsigned int)f2bf(sx) | ((unsigned int)f2bf(sy) << 16);
}

// ---------------- per-graph partial mean from bf16 h (8-way split + float atomics) ----
__global__ void k_gmean(const unsigned short* __restrict__ hb, float* __restrict__ gmean)
{
  const int g = blockIdx.x, l = blockIdx.y, c = blockIdx.z, t = threadIdx.x;  // 64
  const unsigned short* base =
      hb + ((size_t)(l + 1) * N_NODES + (size_t)g * NPG + (size_t)c * (NPG / 8)) * H + t * 2;
  float sx = 0.f, sy = 0.f;
  for (int i = 0; i < 125; ++i) {
    unsigned int u = *(const unsigned int*)(base + (size_t)i * H);
    sx += bf2f((unsigned short)(u & 0xffff));
    sy += bf2f((unsigned short)(u >> 16));
  }
  float* gp = gmean + (size_t)g * (NL * H) + l * H + t * 2;
  atomicAdd(gp, sx);
  atomicAdd(gp + 1, sy);
}

// ---------------- readout ----------------
__global__ __launch_bounds__(128) void k_final(
    const unsigned short* __restrict__ hb, const float* __restrict__ gmean,
    const int* __restrict__ gcount,
    const float* __restrict__ rel_tb, const float* __restrict__ Zn,
    const float* __restrict__ projW, const float* __restrict__ projB,
    const float* __restrict__ fcW, const float* __restrict__ fcB,
    const float* __restrict__ repSeq,
    const int* __restrict__ head_ids, const int* __restrict__ tail_ids,
    const int* __restrict__ rel_lab, float* __restrict__ out)
{
  const int b = blockIdx.x;
  const int o = threadIdx.x;   // 128
  __shared__ float gm[384], hf[384], tf[384];
  __shared__ float go[128], ho[128], t_o[128], re[128], rs[128], sv[128];
  __shared__ float lg[128], pr[128], red[128], att[3];

  const int hid = head_ids[b], tlid = tail_ids[b], rl = rel_lab[b];
  const float cinv = 1.f / (float)gcount[b];
  #pragma unroll
  for (int l = 0; l < NL; ++l) {
    gm[l * H + o] = gmean[(size_t)b * (NL * H) + l * H + o] * cinv;
    hf[l * H + o] = bf2f(hb[((size_t)(l + 1) * N_NODES + hid) * H + o]);
    tf[l * H + o] = bf2f(hb[((size_t)(l + 1) * N_NODES + tlid) * H + o]);
  }
  re[o] = rel_tb[rl * H + o];
  rs[o] = repSeq[b * H + o];
  __syncthreads();

  float pb = projB[o];
  float sg = pb, sh = pb, st = pb;
  for (int i = 0; i < NL * H; ++i) {
    float wv = projW[i * H + o];
    sg = fmaf(gm[i], wv, sg);
    sh = fmaf(hf[i], wv, sh);
    st = fmaf(tf[i], wv, st);
  }
  go[o] = (sg > 0.f) ? sg : 0.01f * sg;
  ho[o] = sh;
  t_o[o] = st;
  __syncthreads();

  {
    const int k = o & 63;
    const float* v = (o < 64) ? ho : t_o;
    float s = 0.f;
    for (int i = 0; i < H; ++i) s = fmaf(v[i], Zn[k * H + i], s);
    lg[o] = s;
  }
  __syncthreads();
  if (o < 2) {
    float* l0 = &lg[o * 64];
    float* p0 = &pr[o * 64];
    float mx = l0[0];
    for (int k = 1; k < 64; ++k) mx = fmaxf(mx, l0[k]);
    float sum = 0.f;
    for (int k = 0; k < 64; ++k) { float e = __expf(l0[k] - mx); p0[k] = e; sum += e; }
    float inv = 1.f / sum;
    for (int k = 0; k < 64; ++k) p0[k] *= inv;
  }
  __syncthreads();
  {
    float s1 = 0.f, s2 = 0.f;
    for (int k = 0; k < 64; ++k) {
      float z = Zn[k * H + o];
      s1 = fmaf(pr[k], z, s1);
      s2 = fmaf(pr[64 + k], z, s2);
    }
    s1 = 1.f / (1.f + __expf(-s1));
    s2 = 1.f / (1.f + __expf(-s2));
    sv[o] = s1 * s2;
  }
  __syncthreads();
  if (o == 0) {
    float d0 = 0.f, d1 = 0.f, d2 = 0.f;
    for (int i = 0; i < H; ++i) { d0 += re[i] * go[i]; d1 += re[i] * rs[i]; d2 += re[i] * sv[i]; }
    float mx = fmaxf(d0, fmaxf(d1, d2));
    float e0 = __expf(d0 - mx), e1 = __expf(d1 - mx), e2 = __expf(d2 - mx);
    float inv = 1.f / (e0 + e1 + e2);
    att[0] = e0 * inv; att[1] = e1 * inv; att[2] = e2 * inv;
  }
  __syncthreads();
  float va = att[0] * go[o] + att[1] * rs[o] + att[2] * sv[o];

  float p = 0.f;
  p = fmaf(hf[o],       fcW[o],       p);
  p = fmaf(hf[128 + o], fcW[128 + o], p);
  p = fmaf(hf[256 + o], fcW[256 + o], p);
  p = fmaf(tf[o],       fcW[384 + o], p);
  p = fmaf(tf[128 + o], fcW[512 + o], p);
  p = fmaf(tf[256 + o], fcW[640 + o], p);
  p = fmaf(re[o],       fcW[768 + o], p);
  p = fmaf(va,          fcW[896 + o], p);
  red[o] = p;
  __syncthreads();
  if (o == 0) {
    float s = 0.f;
    for (int i = 0; i < 128; ++i) s += red[i];
    out[b] = s + fcB[0];
  }
}

extern "C" void kernel_launch(void* const* d_in, const int* in_sizes, int n_in,
                              void* d_out, int out_size, void* d_ws, size_t ws_size,
                              hipStream_t stream) {
  const float* x        = (const float*)d_in[0];
  const float* W_rel    = (const float*)d_in[1];
  const float* W_self   = (const float*)d_in[2];
  const float* rel_tb   = (const float*)d_in[3];
  const float* Zn       = (const float*)d_in[4];
  const float* proj_W   = (const float*)d_in[5];
  const float* proj_b   = (const float*)d_in[6];
  const float* fc_W     = (const float*)d_in[7];
  const float* fc_b     = (const float*)d_in[8];
  const float* rep_seq  = (const float*)d_in[9];
  const int* src      = (const int*)d_in[10];
  const int* dst      = (const int*)d_in[11];
  const int* etype    = (const int*)d_in[12];
  const int* graph_id = (const int*)d_in[13];
  const int* head_ids = (const int*)d_in[14];
  const int* tail_ids = (const int*)d_in[15];
  const int* rel_lab  = (const int*)d_in[16];
  float* out = (float*)d_out;

  // workspace carve (~112 MB), all 16B aligned
  char* w = (char*)d_ws;
  unsigned short* G  = (unsigned short*)w; w += (size_t)N_NODES * NW * 2;              // 73.7 MB
  unsigned short* hb = (unsigned short*)w; w += (size_t)(NL + 1) * N_NODES * H * 2;    // 32.8 MB
  unsigned short* Bt = (unsigned short*)w; w += (size_t)NL * NW * H * 2;               // 0.88 MB
  int* row_ptr  = (int*)w;  w += (size_t)32004 * 4;
  int* edge_off = (int*)w;  w += (size_t)NEDGE * 4;
  // zero region: cursor | gcount | gmean
  char* z = w;
  int* cursor  = (int*)w;   w += (size_t)N_NODES * 4;
  int* gcount  = (int*)w;   w += (size_t)32 * 4;
  float* gmean = (float*)w; w += (size_t)BSZ * NL * H * 4;
  size_t zbytes = (size_t)(w - z);

  hipMemsetAsync(z, 0, zbytes, stream);
  k_count <<<NEDGE / 256, 256, 0, stream>>>(dst, cursor);
  k_scan  <<<1, 256, 0, stream>>>(cursor, row_ptr);
  k_fill  <<<NEDGE / 256, 256, 0, stream>>>(src, dst, etype, cursor, edge_off);
  k_gcount<<<(N_NODES + 255) / 256, 256, 0, stream>>>(graph_id, gcount);
  k_cvtX  <<<(N_NODES * H) / (256 * 4), 256, 0, stream>>>(x, hb);
  k_cvtB  <<<(NL * NW * H) / 256, 256, 0, stream>>>(W_rel, W_self, Bt);

  for (int l = 0; l < NL; ++l) {
    const unsigned short* hp = hb + (size_t)l * N_NODES * H;
    unsigned short* hn = hb + (size_t)(l + 1) * N_NODES * H;
    k_gemm9 <<<dim3(N_NODES / 128, 9), 256, 0, stream>>>(hp, Bt + (size_t)l * NW * H, G);
    k_gather<<<N_NODES / 4, 256, 0, stream>>>(G, row_ptr, edge_off, hn);
  }
  k_gmean<<<dim3(BSZ, NL, 8), 64, 0, stream>>>(hb, gmean);
  k_final<<<BSZ, H, 0, stream>>>(hb, gmean, gcount, rel_tb, Zn, proj_W, proj_b, fc_W, fc_b,
                                 rep_seq, head_ids, tail_ids, rel_lab, out);
  (void)in_sizes; (void)n_in; (void)out_size; (void)ws_size;
}